// Round 3
// baseline (209.116 us; speedup 1.0000x reference)
//
#include <hip/hip_runtime.h>
#include <math.h>

// ---------------- problem constants ----------------
#define N_TOTAL 2097024
#define HWF (1024 * 1536)

#define OFF0 0
#define OFF1 1572864
#define OFF2 1966080
#define OFF3 2064384
#define OFF4 2088960
#define OFF5 2095104
#define OFF6 2096640

// output section offsets (floats)
#define OUT_LS   (3 * HWF)
#define OUT_DEC  (6 * HWF)
#define OUT_RATE (9 * HWF)

// float4 with 4-byte alignment (windows are only dword-aligned)
typedef float f4 __attribute__((ext_vector_type(4), aligned(4)));
typedef float float4v __attribute__((ext_vector_type(4)));
typedef _Float16 half4 __attribute__((ext_vector_type(4)));
typedef _Float16 half8 __attribute__((ext_vector_type(8)));

// ---------------- softround ----------------
__device__ __forceinline__ float softround_f(float x) {
    const float INV_T = 1.0f / 0.3f;
    const float HALF_OVER_TANH = 0.53699381f; // 0.5 / tanh(0.5/0.3)
    float fl = floorf(x);
    return fl + tanhf((x - fl - 0.5f) * INV_T) * HALF_OVER_TANH + 0.5f;
}

// ---------------- kernel 1: quantization ----------------
__global__ void quant_kernel(const float* __restrict__ l0, const float* __restrict__ l1,
                             const float* __restrict__ l2, const float* __restrict__ l3,
                             const float* __restrict__ l4, const float* __restrict__ l5,
                             const float* __restrict__ l6, const float* __restrict__ noise,
                             float* __restrict__ flat_q) {
    int idx = blockIdx.x * blockDim.x + threadIdx.x;
    if (idx >= N_TOTAL) return;
    float v;
    if      (idx < OFF1) v = l0[idx - OFF0];
    else if (idx < OFF2) v = l1[idx - OFF1];
    else if (idx < OFF3) v = l2[idx - OFF2];
    else if (idx < OFF4) v = l3[idx - OFF3];
    else if (idx < OFF5) v = l4[idx - OFF4];
    else if (idx < OFF6) v = l5[idx - OFF5];
    else                 v = l6[idx - OFF6];
    float x = v * 16.0f;                       // GAIN
    float s1 = softround_f(x);
    float s2 = softround_f(s1 + noise[idx] - 0.5f);
    flat_q[idx] = s2;
}

// ---------------- kernel 2: context + ARM MLP + rate ----------------
__global__ void arm_kernel(const float* __restrict__ flat_q, int off, int h, int w,
                           const float* __restrict__ w1, const float* __restrict__ b1,
                           const float* __restrict__ w2, const float* __restrict__ b2,
                           const float* __restrict__ wo, const float* __restrict__ bo,
                           float* __restrict__ rate_out) {
    __shared__ float sw1[256], sb1[16], sw2[256], sb2[16], swo[32], sbo[2];
    int t = threadIdx.y * blockDim.x + threadIdx.x;
    for (int i = t; i < 256; i += 256) { sw1[i] = w1[i]; sw2[i] = w2[i]; }
    if (t < 16) { sb1[t] = b1[t]; sb2[t] = b2[t]; }
    if (t < 32) swo[t] = wo[t];
    if (t < 2)  sbo[t] = bo[t];
    __syncthreads();

    int x = blockIdx.x * blockDim.x + threadIdx.x;
    int y = blockIdx.y * blockDim.y + threadIdx.y;
    if (x >= w || y >= h) return;
    const float* g = flat_q + off;

    const int DY[16] = {-3,-3,-3,-2,-2,-2,-2,-2,-1,-1,-1,-1,-1,-1, 0, 0};
    const int DX[16] = {-1, 0, 1,-2,-1, 0, 1, 2,-3,-2,-1, 0, 1, 2,-2,-1};
    float ctx[16];
#pragma unroll
    for (int k = 0; k < 16; k++) {
        int yy = y + DY[k], xx = x + DX[k];
        ctx[k] = (yy >= 0 && yy < h && xx >= 0 && xx < w) ? g[yy * w + xx] : 0.0f;
    }

    float h1[16];
#pragma unroll
    for (int j = 0; j < 16; j++) {
        float acc = sb1[j] + ctx[j];
#pragma unroll
        for (int k = 0; k < 16; k++) acc = fmaf(sw1[j * 16 + k], ctx[k], acc);
        h1[j] = fmaxf(acc, 0.0f);
    }
    float h2[16];
#pragma unroll
    for (int j = 0; j < 16; j++) {
        float acc = sb2[j] + h1[j];
#pragma unroll
        for (int k = 0; k < 16; k++) acc = fmaf(sw2[j * 16 + k], h1[k], acc);
        h2[j] = fmaxf(acc, 0.0f);
    }
    float mu = sbo[0], ls = sbo[1];
#pragma unroll
    for (int k = 0; k < 16; k++) {
        mu = fmaf(swo[k], h2[k], mu);
        ls = fmaf(swo[16 + k], h2[k], ls);
    }
    ls = fminf(fmaxf(ls, -13.8155f), 13.8155f);
    float inv_scale = expf(0.5f * ls);

    float q = g[y * w + x];
    float da = (q + 0.5f) - mu;
    float db = (q - 0.5f) - mu;
    float la = 0.5f - 0.5f * copysignf(1.0f, da) * expm1f(-fabsf(da) * inv_scale);
    float lb = 0.5f - 0.5f * copysignf(1.0f, db) * expm1f(-fabsf(db) * inv_scale);
    float proba = fmaxf(la - lb, 1.52587890625e-05f);
    rate_out[off + y * w + x] = -log2f(proba);
}

// ---------------- quad helpers (separable, register-resident) ----------------
__device__ __forceinline__ void up_quad(const float* __restrict__ in, int H, int W,
                                        int i, int j, const float* K, float o[4]) {
    float w[5][5];
    bool interior = (i >= 2 && i <= H - 3 && j >= 2 && j <= W - 3);
    if (interior) {
        const float* p = in + (i - 2) * W + (j - 2);
#pragma unroll
        for (int r = 0; r < 5; r++) {
            f4 a = *(const f4*)p;
            w[r][0] = a.x; w[r][1] = a.y; w[r][2] = a.z; w[r][3] = a.w;
            w[r][4] = p[4];
            p += W;
        }
    } else {
#pragma unroll
        for (int r = 0; r < 5; r++)
#pragma unroll
            for (int e = 0; e < 5; e++) {
                int yy = i - 2 + r, xx = j - 2 + e;
                w[r][e] = (yy >= 0 && yy < H && xx >= 0 && xx < W) ? in[yy * W + xx] : 0.0f;
            }
    }
    float h0[5], h1[5];
#pragma unroll
    for (int r = 0; r < 5; r++) {
        h0[r] = K[0]*w[r][0] + K[2]*w[r][1] + K[4]*w[r][2] + K[6]*w[r][3];
        h1[r] = K[1]*w[r][1] + K[3]*w[r][2] + K[5]*w[r][3] + K[7]*w[r][4];
    }
    o[0] = K[0]*h0[0] + K[2]*h0[1] + K[4]*h0[2] + K[6]*h0[3];
    o[1] = K[0]*h1[0] + K[2]*h1[1] + K[4]*h1[2] + K[6]*h1[3];
    o[2] = K[1]*h0[1] + K[3]*h0[2] + K[5]*h0[3] + K[7]*h0[4];
    o[3] = K[1]*h1[1] + K[3]*h1[2] + K[5]*h1[3] + K[7]*h1[4];
}

__device__ __forceinline__ void conv7_quad(const float* __restrict__ dec, int H, int W,
                                           int i, int j, const float* k, float o[4]) {
    int Y = 2 * i, X = 2 * j;
    float g0[8], g1[8];
    bool interior = (Y - 3 >= 0 && Y + 4 <= H - 1 && X - 3 >= 0 && X + 4 <= W - 1);
    if (interior) {
        const float* p = dec + (Y - 3) * W + (X - 3);
#pragma unroll
        for (int r = 0; r < 8; r++) {
            f4 a = *(const f4*)p;
            f4 b = *(const f4*)(p + 4);
            g0[r] = k[0]*a.x + k[1]*a.y + k[2]*a.z + k[3]*a.w + k[4]*b.x + k[5]*b.y + k[6]*b.z;
            g1[r] = k[0]*a.y + k[1]*a.z + k[2]*a.w + k[3]*b.x + k[4]*b.y + k[5]*b.z + k[6]*b.w;
            p += W;
        }
    } else {
#pragma unroll
        for (int r = 0; r < 8; r++) {
            float wv[8];
#pragma unroll
            for (int q = 0; q < 8; q++) {
                int yy = Y - 3 + r, xx = X - 3 + q;
                wv[q] = (yy >= 0 && yy < H && xx >= 0 && xx < W) ? dec[yy * W + xx] : 0.0f;
            }
            g0[r] = k[0]*wv[0] + k[1]*wv[1] + k[2]*wv[2] + k[3]*wv[3] + k[4]*wv[4] + k[5]*wv[5] + k[6]*wv[6];
            g1[r] = k[0]*wv[1] + k[1]*wv[2] + k[2]*wv[3] + k[3]*wv[4] + k[4]*wv[5] + k[5]*wv[6] + k[6]*wv[7];
        }
    }
    o[0] = k[0]*g0[0] + k[1]*g0[1] + k[2]*g0[2] + k[3]*g0[3] + k[4]*g0[4] + k[5]*g0[5] + k[6]*g0[6];
    o[1] = k[0]*g1[0] + k[1]*g1[1] + k[2]*g1[2] + k[3]*g1[3] + k[4]*g1[4] + k[5]*g1[5] + k[6]*g1[6];
    o[2] = k[0]*g0[1] + k[1]*g0[2] + k[2]*g0[3] + k[3]*g0[4] + k[4]*g0[5] + k[5]*g0[6] + k[6]*g0[7];
    o[3] = k[0]*g1[1] + k[1]*g1[2] + k[2]*g1[3] + k[3]*g1[4] + k[4]*g1[5] + k[5]*g1[6] + k[6]*g1[7];
}

// ---------------- kernel 3: intermediate pyramid step (quad per thread) ----------------
__global__ void pyramid_quad_kernel(const float* __restrict__ xin, int hin, int win_,
                                    const float* __restrict__ dec,
                                    const float* __restrict__ upsk, const float* __restrict__ prek,
                                    float* __restrict__ xout, int hout, int wout) {
    int qw = wout >> 1, qh = hout >> 1;
    int j = blockIdx.x * blockDim.x + threadIdx.x;
    int i = blockIdx.y * blockDim.y + threadIdx.y;
    int c = blockIdx.z;
    if (j >= qw || i >= qh) return;
    float o[4];
    if (c == 0) {
        float k[7];
#pragma unroll
        for (int p = 0; p < 7; p++) k[p] = prek[p];
        conv7_quad(dec, hout, wout, i, j, k, o);
    } else {
        float K[8];
#pragma unroll
        for (int p = 0; p < 8; p++) K[p] = upsk[p];
        up_quad(xin + (size_t)(c - 1) * hin * win_, hin, win_, i, j, K, o);
    }
    size_t base = ((size_t)c * hout + 2 * i) * wout + 2 * j;
    *(float2*)(xout + base)        = make_float2(o[0], o[1]);
    *(float2*)(xout + base + wout) = make_float2(o[2], o[3]);
}

// ---------------- kernel 4: fused final pyramid step + MFMA synthesis ----------------
// Layer1 (swapped): D1[j][px] = sum_k W1ext[j][k] * Xext[k][px]   (k: 7 ch + bias-one, pad 16)
// Layer2 (swapped): D2[o][px] = sum_j W2[o][j] * relu(D1)[j][px]  (j: 48 = 3 K-tiles)
// C layout of D1 (col=px=lane&15, row=4*(lane>>4)+reg) IS the B layout of layer2 -> no transpose.
__global__ __launch_bounds__(256) void final_kernel(
    const float* __restrict__ up_in,  // 6 ch @ 512x768
    const float* __restrict__ dec0,   // 1024x1536
    const float* __restrict__ upsk, const float* __restrict__ prek,
    const float* __restrict__ w1, const float* __restrict__ b1,
    const float* __restrict__ w2, const float* __restrict__ b2,
    float* __restrict__ out) {
    // per-wave staging tile: 256 px * 8 ch f16 = 4 KB
    __shared__ __align__(16) _Float16 stage[4][2048];

    const int H2_ = 512, W2_ = 768, H1_ = 1024, W1_ = 1536;
    int t = threadIdx.x;
    int lane = t & 63, wv = t >> 6;
    int lo = lane & 15, lhi = lane >> 4;

    // ---- per-lane weight fragments ----
    half4 a1f[3], a2f[3];
#pragma unroll
    for (int T = 0; T < 3; T++) {
        int j = lo + 16 * T;
#pragma unroll
        for (int i = 0; i < 4; i++) {
            int k = 4 * lhi + i;
            float v1 = 0.0f;
            if (lhi < 2) v1 = (k < 7) ? w1[j * 7 + k] : ((k == 7) ? b1[j] : 0.0f);
            a1f[T][i] = (_Float16)v1;
            float v2 = (lo < 6) ? w2[lo * 48 + 16 * T + k] : 0.0f;
            a2f[T][i] = (_Float16)v2;
        }
    }
    float4v c2init = {0.f, 0.f, 0.f, 0.f};
#pragma unroll
    for (int i = 0; i < 4; i++) {
        int m = 4 * lhi + i;
        c2init[i] = (m < 6) ? b2[m] : 0.0f;
    }

    // ---- upsample phase: one 2x2 quad per thread ----
    int qx = t & 15, qy = t >> 4;                // quad coords in 16x16 block tile
    int j = blockIdx.x * 16 + qx;                // quad col [0,768)
    int i = blockIdx.y * 16 + qy;                // quad row [0,512)

    float K[8], kp[7];
#pragma unroll
    for (int p = 0; p < 8; p++) K[p] = upsk[p];
#pragma unroll
    for (int p = 0; p < 7; p++) kp[p] = prek[p];

    float px0[7], px1[7], px2[7], px3[7];
    {
        float o[4];
        conv7_quad(dec0, H1_, W1_, i, j, kp, o);
        px0[0] = o[0]; px1[0] = o[1]; px2[0] = o[2]; px3[0] = o[3];
    }
#pragma unroll
    for (int c = 0; c < 6; c++) {
        float o[4];
        up_quad(up_in + (size_t)c * (H2_ * W2_), H2_, W2_, i, j, K, o);
        px0[c + 1] = o[0]; px1[c + 1] = o[1]; px2[c + 1] = o[2]; px3[c + 1] = o[3];
    }

    // ---- stage to LDS (wave-local, f16, bias-one channel) ----
    _Float16* sbase = stage[wv];
    int qyl = qy & 3;                 // quad row within wave
    int r0 = 2 * qyl, x0 = 2 * qx;    // px coords within wave tile (8 rows x 32 cols)
    {
        const float* pxs[4] = {px0, px1, px2, px3};
        const int rr[4] = {r0, r0, r0 + 1, r0 + 1};
        const int xx[4] = {x0, x0 + 1, x0, x0 + 1};
#pragma unroll
        for (int q = 0; q < 4; q++) {
            half8 hv;
#pragma unroll
            for (int c = 0; c < 7; c++) hv[c] = (_Float16)pxs[q][c];
            hv[7] = (_Float16)1.0f;
            *reinterpret_cast<half8*>(sbase + ((rr[q] * 32 + xx[q]) << 3)) = hv;
        }
    }
    // wave-local LDS dependency: compiler inserts lgkmcnt wait; no barrier needed.

    // ---- MFMA phase: 16 groups of 16 consecutive px per wave ----
    int by32 = blockIdx.y * 32, bx32 = blockIdx.x * 32;
    const float4v zero4 = {0.f, 0.f, 0.f, 0.f};
#pragma unroll 2
    for (int g = 0; g < 16; g++) {
        int r = g >> 1, hh = g & 1;
        half4 bf = {};
        if (lhi < 2)
            bf = *reinterpret_cast<const half4*>(sbase + (((r * 32 + hh * 16 + lo) << 3) + (lhi << 2)));
        float4v acc = c2init;
#pragma unroll
        for (int T = 0; T < 3; T++) {
            float4v d1 = __builtin_amdgcn_mfma_f32_16x16x16f16(a1f[T], bf, zero4, 0, 0, 0);
            half4 hp;
#pragma unroll
            for (int q = 0; q < 4; q++) hp[q] = (_Float16)fmaxf(d1[q], 0.0f);
            acc = __builtin_amdgcn_mfma_f32_16x16x16f16(a2f[T], hp, acc, 0, 0, 0);
        }
        // store: lane holds px = lo of this group, outputs m = 4*lhi + reg
        int Y = by32 + 8 * wv + r;
        size_t p = (size_t)Y * W1_ + bx32 + 16 * hh + lo;
        if (lhi == 0) {
            out[p]               = acc[0];
            out[HWF + p]         = acc[1];
            out[2 * HWF + p]     = acc[2];
            out[OUT_LS + p]      = acc[3];
            out[OUT_DEC + p]           = fminf(fmaxf(acc[0], 0.0f), 1.0f);
            out[OUT_DEC + HWF + p]     = fminf(fmaxf(acc[1], 0.0f), 1.0f);
            out[OUT_DEC + 2 * HWF + p] = fminf(fmaxf(acc[2], 0.0f), 1.0f);
        } else if (lhi == 1) {
            out[OUT_LS + HWF + p]     = acc[0];
            out[OUT_LS + 2 * HWF + p] = acc[1];
        }
    }
}

// ---------------- launch ----------------
extern "C" void kernel_launch(void* const* d_in, const int* in_sizes, int n_in,
                              void* d_out, int out_size, void* d_ws, size_t ws_size,
                              hipStream_t stream) {
    const float* lat[7];
    for (int i = 0; i < 7; i++) lat[i] = (const float*)d_in[i];
    const float* noise  = (const float*)d_in[7];
    const float* arm_w1 = (const float*)d_in[8];
    const float* arm_b1 = (const float*)d_in[9];
    const float* arm_w2 = (const float*)d_in[10];
    const float* arm_b2 = (const float*)d_in[11];
    const float* arm_wo = (const float*)d_in[12];
    const float* arm_bo = (const float*)d_in[13];
    const float* ups_k  = (const float*)d_in[14]; // (6,8)
    const float* pre_k  = (const float*)d_in[15]; // (6,7)
    const float* syn_w1 = (const float*)d_in[16]; // (48,7)
    const float* syn_b1 = (const float*)d_in[17];
    const float* syn_w2 = (const float*)d_in[18]; // (6,48)
    const float* syn_b2 = (const float*)d_in[19];
    float* out = (float*)d_out;

    float* flat_q = (float*)d_ws;                 // N_TOTAL
    float* bufA   = flat_q + N_TOTAL;             // up to 6*512*768
    float* bufB   = bufA + 6 * 512 * 768;         // up to 5*256*384

    static const int SH[7]  = {1024, 512, 256, 128, 64, 32, 16};
    static const int SW[7]  = {1536, 768, 384, 192, 96, 48, 24};
    static const int OFF[7] = {OFF0, OFF1, OFF2, OFF3, OFF4, OFF5, OFF6};

    // 1. quantization
    quant_kernel<<<(N_TOTAL + 255) / 256, 256, 0, stream>>>(
        lat[0], lat[1], lat[2], lat[3], lat[4], lat[5], lat[6], noise, flat_q);

    // 2. ARM + rate
    for (int g = 0; g < 7; g++) {
        dim3 blk(32, 8);
        dim3 grd((SW[g] + 31) / 32, (SH[g] + 7) / 8);
        arm_kernel<<<grd, blk, 0, stream>>>(flat_q, OFF[g], SH[g], SW[g],
                                            arm_w1, arm_b1, arm_w2, arm_b2,
                                            arm_wo, arm_bo, out + OUT_RATE);
    }

    // 3. intermediate pyramid steps s=0..4 (quad kernels), ping-pong bufA/bufB
    const float* xin = flat_q + OFF6; // dec[6], 1ch 16x24
    float* bufs[2] = {bufA, bufB};
    for (int s = 0; s < 5; s++) {
        int i    = 6 - s;
        int hin  = SH[i], win_ = SW[i];
        int hout = SH[i - 1], wout = SW[i - 1];
        int cin  = s + 1;
        float* xout = bufs[s & 1];
        dim3 blk(16, 16);
        dim3 grd((wout / 2 + 15) / 16, (hout / 2 + 15) / 16, cin + 1);
        pyramid_quad_kernel<<<grd, blk, 0, stream>>>(xin, hin, win_,
                                                     flat_q + OFF[i - 1],
                                                     ups_k + s * 8, pre_k + s * 7,
                                                     xout, hout, wout);
        xin = xout;
    }

    // 4. fused final step + MFMA synthesis
    dim3 fgrd(768 / 16, 512 / 16);
    final_kernel<<<fgrd, 256, 0, stream>>>(bufA, flat_q,
                                           ups_k + 5 * 8, pre_k + 5 * 7,
                                           syn_w1, syn_b1, syn_w2, syn_b2, out);
}

// Round 4
// 149.562 us; speedup vs baseline: 1.3982x; 1.3982x over previous
//
#include <hip/hip_runtime.h>
#include <math.h>

// ---------------- problem constants ----------------
#define N_TOTAL 2097024
#define HWF (1024 * 1536)

#define OFF0 0
#define OFF1 1572864
#define OFF2 1966080
#define OFF3 2064384
#define OFF4 2088960
#define OFF5 2095104
#define OFF6 2096640

// output section offsets (floats)
#define OUT_LS   (3 * HWF)
#define OUT_DEC  (6 * HWF)
#define OUT_RATE (9 * HWF)

// float4 with 4-byte alignment (windows are only dword-aligned)
typedef float f4 __attribute__((ext_vector_type(4), aligned(4)));

// ---------------- softround ----------------
__device__ __forceinline__ float softround_f(float x) {
    const float INV_T = 1.0f / 0.3f;
    const float HALF_OVER_TANH = 0.53699381f; // 0.5 / tanh(0.5/0.3)
    float fl = floorf(x);
    return fl + tanhf((x - fl - 0.5f) * INV_T) * HALF_OVER_TANH + 0.5f;
}

// ---------------- kernel 1: quantization ----------------
__global__ void quant_kernel(const float* __restrict__ l0, const float* __restrict__ l1,
                             const float* __restrict__ l2, const float* __restrict__ l3,
                             const float* __restrict__ l4, const float* __restrict__ l5,
                             const float* __restrict__ l6, const float* __restrict__ noise,
                             float* __restrict__ flat_q) {
    int idx = blockIdx.x * blockDim.x + threadIdx.x;
    if (idx >= N_TOTAL) return;
    float v;
    if      (idx < OFF1) v = l0[idx - OFF0];
    else if (idx < OFF2) v = l1[idx - OFF1];
    else if (idx < OFF3) v = l2[idx - OFF2];
    else if (idx < OFF4) v = l3[idx - OFF3];
    else if (idx < OFF5) v = l4[idx - OFF4];
    else if (idx < OFF6) v = l5[idx - OFF5];
    else                 v = l6[idx - OFF6];
    float x = v * 16.0f;                       // GAIN
    float s1 = softround_f(x);
    float s2 = softround_f(s1 + noise[idx] - 0.5f);
    flat_q[idx] = s2;
}

// ---------------- kernel 2: fused ARM over all 7 grids ----------------
// Weights read with wave-uniform addresses -> scalar loads via constant cache.
template <int H, int W, int OFFT>
__device__ __forceinline__ void arm_body(const float* __restrict__ flat_q, int pos,
                                         const float* __restrict__ w1, const float* __restrict__ b1,
                                         const float* __restrict__ w2, const float* __restrict__ b2,
                                         const float* __restrict__ wo, const float* __restrict__ bo,
                                         float* __restrict__ rate_out) {
    if (pos >= H * W) return;
    unsigned up = (unsigned)pos;
    int y = up / (unsigned)W;
    int x = pos - y * W;
    const float* g = flat_q + OFFT;

    const int DY[16] = {-3,-3,-3,-2,-2,-2,-2,-2,-1,-1,-1,-1,-1,-1, 0, 0};
    const int DX[16] = {-1, 0, 1,-2,-1, 0, 1, 2,-3,-2,-1, 0, 1, 2,-2,-1};
    float ctx[16];
#pragma unroll
    for (int k = 0; k < 16; k++) {
        int yy = y + DY[k], xx = x + DX[k];
        ctx[k] = (yy >= 0 && yy < H && xx >= 0 && xx < W) ? g[yy * W + xx] : 0.0f;
    }

    float h1[16];
#pragma unroll 4
    for (int j = 0; j < 16; j++) {
        float acc = b1[j] + ctx[j];
#pragma unroll
        for (int k = 0; k < 16; k++) acc = fmaf(w1[j * 16 + k], ctx[k], acc);
        h1[j] = fmaxf(acc, 0.0f);
    }
    float h2[16];
#pragma unroll 4
    for (int j = 0; j < 16; j++) {
        float acc = b2[j] + h1[j];
#pragma unroll
        for (int k = 0; k < 16; k++) acc = fmaf(w2[j * 16 + k], h1[k], acc);
        h2[j] = fmaxf(acc, 0.0f);
    }
    float mu = bo[0], ls = bo[1];
#pragma unroll
    for (int k = 0; k < 16; k++) {
        mu = fmaf(wo[k], h2[k], mu);
        ls = fmaf(wo[16 + k], h2[k], ls);
    }
    ls = fminf(fmaxf(ls, -13.8155f), 13.8155f);
    float inv_scale = expf(0.5f * ls);

    float q = g[(size_t)y * W + x];
    float da = (q + 0.5f) - mu;
    float db = (q - 0.5f) - mu;
    float la = 0.5f - 0.5f * copysignf(1.0f, da) * expm1f(-fabsf(da) * inv_scale);
    float lb = 0.5f - 0.5f * copysignf(1.0f, db) * expm1f(-fabsf(db) * inv_scale);
    float proba = fmaxf(la - lb, 1.52587890625e-05f);
    rate_out[OFFT + pos] = -log2f(proba);
}

// block-count prefix: per-grid blocks = h*w/256 (g6 rounded up)
// g0:6144 g1:1536 g2:384 g3:96 g4:24 g5:6 g6:2  -> cum 6144,7680,8064,8160,8184,8190,8192
__global__ __launch_bounds__(256) void arm_all_kernel(
    const float* __restrict__ flat_q,
    const float* __restrict__ w1, const float* __restrict__ b1,
    const float* __restrict__ w2, const float* __restrict__ b2,
    const float* __restrict__ wo, const float* __restrict__ bo,
    float* __restrict__ rate_out) {
    int b = blockIdx.x;
    int t = threadIdx.x;
    if (b < 6144) {
        arm_body<1024, 1536, OFF0>(flat_q, b * 256 + t, w1, b1, w2, b2, wo, bo, rate_out);
    } else if (b < 7680) {
        arm_body<512, 768, OFF1>(flat_q, (b - 6144) * 256 + t, w1, b1, w2, b2, wo, bo, rate_out);
    } else if (b < 8064) {
        arm_body<256, 384, OFF2>(flat_q, (b - 7680) * 256 + t, w1, b1, w2, b2, wo, bo, rate_out);
    } else if (b < 8160) {
        arm_body<128, 192, OFF3>(flat_q, (b - 8064) * 256 + t, w1, b1, w2, b2, wo, bo, rate_out);
    } else if (b < 8184) {
        arm_body<64, 96, OFF4>(flat_q, (b - 8160) * 256 + t, w1, b1, w2, b2, wo, bo, rate_out);
    } else if (b < 8190) {
        arm_body<32, 48, OFF5>(flat_q, (b - 8184) * 256 + t, w1, b1, w2, b2, wo, bo, rate_out);
    } else {
        arm_body<16, 24, OFF6>(flat_q, (b - 8190) * 256 + t, w1, b1, w2, b2, wo, bo, rate_out);
    }
}

// ---------------- quad helpers (separable, register-resident) ----------------
__device__ __forceinline__ void up_quad(const float* __restrict__ in, int H, int W,
                                        int i, int j, const float* K, float o[4]) {
    float w[5][5];
    bool interior = (i >= 2 && i <= H - 3 && j >= 2 && j <= W - 3);
    if (interior) {
        const float* p = in + (i - 2) * W + (j - 2);
#pragma unroll
        for (int r = 0; r < 5; r++) {
            f4 a = *(const f4*)p;
            w[r][0] = a.x; w[r][1] = a.y; w[r][2] = a.z; w[r][3] = a.w;
            w[r][4] = p[4];
            p += W;
        }
    } else {
#pragma unroll
        for (int r = 0; r < 5; r++)
#pragma unroll
            for (int e = 0; e < 5; e++) {
                int yy = i - 2 + r, xx = j - 2 + e;
                w[r][e] = (yy >= 0 && yy < H && xx >= 0 && xx < W) ? in[yy * W + xx] : 0.0f;
            }
    }
    float h0[5], h1[5];
#pragma unroll
    for (int r = 0; r < 5; r++) {
        h0[r] = K[0]*w[r][0] + K[2]*w[r][1] + K[4]*w[r][2] + K[6]*w[r][3];
        h1[r] = K[1]*w[r][1] + K[3]*w[r][2] + K[5]*w[r][3] + K[7]*w[r][4];
    }
    o[0] = K[0]*h0[0] + K[2]*h0[1] + K[4]*h0[2] + K[6]*h0[3];
    o[1] = K[0]*h1[0] + K[2]*h1[1] + K[4]*h1[2] + K[6]*h1[3];
    o[2] = K[1]*h0[1] + K[3]*h0[2] + K[5]*h0[3] + K[7]*h0[4];
    o[3] = K[1]*h1[1] + K[3]*h1[2] + K[5]*h1[3] + K[7]*h1[4];
}

__device__ __forceinline__ void conv7_quad(const float* __restrict__ dec, int H, int W,
                                           int i, int j, const float* k, float o[4]) {
    int Y = 2 * i, X = 2 * j;
    float g0[8], g1[8];
    bool interior = (Y - 3 >= 0 && Y + 4 <= H - 1 && X - 3 >= 0 && X + 4 <= W - 1);
    if (interior) {
        const float* p = dec + (Y - 3) * W + (X - 3);
#pragma unroll
        for (int r = 0; r < 8; r++) {
            f4 a = *(const f4*)p;
            f4 b = *(const f4*)(p + 4);
            g0[r] = k[0]*a.x + k[1]*a.y + k[2]*a.z + k[3]*a.w + k[4]*b.x + k[5]*b.y + k[6]*b.z;
            g1[r] = k[0]*a.y + k[1]*a.z + k[2]*a.w + k[3]*b.x + k[4]*b.y + k[5]*b.z + k[6]*b.w;
            p += W;
        }
    } else {
#pragma unroll
        for (int r = 0; r < 8; r++) {
            float wv[8];
#pragma unroll
            for (int q = 0; q < 8; q++) {
                int yy = Y - 3 + r, xx = X - 3 + q;
                wv[q] = (yy >= 0 && yy < H && xx >= 0 && xx < W) ? dec[yy * W + xx] : 0.0f;
            }
            g0[r] = k[0]*wv[0] + k[1]*wv[1] + k[2]*wv[2] + k[3]*wv[3] + k[4]*wv[4] + k[5]*wv[5] + k[6]*wv[6];
            g1[r] = k[0]*wv[1] + k[1]*wv[2] + k[2]*wv[3] + k[3]*wv[4] + k[4]*wv[5] + k[5]*wv[6] + k[6]*wv[7];
        }
    }
    o[0] = k[0]*g0[0] + k[1]*g0[1] + k[2]*g0[2] + k[3]*g0[3] + k[4]*g0[4] + k[5]*g0[5] + k[6]*g0[6];
    o[1] = k[0]*g1[0] + k[1]*g1[1] + k[2]*g1[2] + k[3]*g1[3] + k[4]*g1[4] + k[5]*g1[5] + k[6]*g1[6];
    o[2] = k[0]*g0[1] + k[1]*g0[2] + k[2]*g0[3] + k[3]*g0[4] + k[4]*g0[5] + k[5]*g0[6] + k[6]*g0[7];
    o[3] = k[0]*g1[1] + k[1]*g1[2] + k[2]*g1[3] + k[3]*g1[4] + k[4]*g1[5] + k[5]*g1[6] + k[6]*g1[7];
}

// ---------------- kernel 3: intermediate pyramid step (quad per thread) ----------------
__global__ void pyramid_quad_kernel(const float* __restrict__ xin, int hin, int win_,
                                    const float* __restrict__ dec,
                                    const float* __restrict__ upsk, const float* __restrict__ prek,
                                    float* __restrict__ xout, int hout, int wout) {
    int qw = wout >> 1, qh = hout >> 1;
    int j = blockIdx.x * blockDim.x + threadIdx.x;
    int i = blockIdx.y * blockDim.y + threadIdx.y;
    int c = blockIdx.z;
    if (j >= qw || i >= qh) return;
    float o[4];
    if (c == 0) {
        float k[7];
#pragma unroll
        for (int p = 0; p < 7; p++) k[p] = prek[p];
        conv7_quad(dec, hout, wout, i, j, k, o);
    } else {
        float K[8];
#pragma unroll
        for (int p = 0; p < 8; p++) K[p] = upsk[p];
        up_quad(xin + (size_t)(c - 1) * hin * win_, hin, win_, i, j, K, o);
    }
    size_t base = ((size_t)c * hout + 2 * i) * wout + 2 * j;
    *(float2*)(xout + base)        = make_float2(o[0], o[1]);
    *(float2*)(xout + base + wout) = make_float2(o[2], o[3]);
}

// ---------------- kernel 4: fused final pyramid step + synthesis (VALU, scalar weights) ----------------
__global__ __launch_bounds__(256) void final_kernel(
    const float* __restrict__ up_in,  // 6 ch @ 512x768
    const float* __restrict__ dec0,   // 1024x1536
    const float* __restrict__ upsk, const float* __restrict__ prek,
    const float* __restrict__ w1, const float* __restrict__ b1,
    const float* __restrict__ w2, const float* __restrict__ b2,
    float* __restrict__ out) {
    const int H2_ = 512, W2_ = 768, H1_ = 1024, W1_ = 1536;
    int t = threadIdx.x;
    int j = blockIdx.x * 16 + (t & 15);   // quad col, [0,768)
    int i = blockIdx.y * 16 + (t >> 4);   // quad row, [0,512)

    float K[8], kp[7];
#pragma unroll
    for (int p = 0; p < 8; p++) K[p] = upsk[p];
#pragma unroll
    for (int p = 0; p < 7; p++) kp[p] = prek[p];

    // px[q][ch]: q = 0:(2i,2j) 1:(2i,2j+1) 2:(2i+1,2j) 3:(2i+1,2j+1)
    float px0[7], px1[7], px2[7], px3[7];
    {
        float o[4];
        conv7_quad(dec0, H1_, W1_, i, j, kp, o);
        px0[0] = o[0]; px1[0] = o[1]; px2[0] = o[2]; px3[0] = o[3];
    }
#pragma unroll
    for (int c = 0; c < 6; c++) {
        float o[4];
        up_quad(up_in + (size_t)c * (H2_ * W2_), H2_, W2_, i, j, K, o);
        px0[c + 1] = o[0]; px1[c + 1] = o[1]; px2[c + 1] = o[2]; px3[c + 1] = o[3];
    }

    // synthesis MLP: weights via wave-uniform global loads (constant cache)
    float o0[6], o1[6], o2[6], o3[6];
#pragma unroll
    for (int q = 0; q < 6; q++) {
        float bq = b2[q];
        o0[q] = bq; o1[q] = bq; o2[q] = bq; o3[q] = bq;
    }
#pragma unroll 4
    for (int k = 0; k < 48; k++) {
        float bk = b1[k];
        float a0 = bk, a1 = bk, a2 = bk, a3 = bk;
#pragma unroll
        for (int c = 0; c < 7; c++) {
            float wk = w1[k * 7 + c];
            a0 = fmaf(wk, px0[c], a0);
            a1 = fmaf(wk, px1[c], a1);
            a2 = fmaf(wk, px2[c], a2);
            a3 = fmaf(wk, px3[c], a3);
        }
        a0 = fmaxf(a0, 0.0f); a1 = fmaxf(a1, 0.0f); a2 = fmaxf(a2, 0.0f); a3 = fmaxf(a3, 0.0f);
#pragma unroll
        for (int q = 0; q < 6; q++) {
            float wj = w2[q * 48 + k];
            o0[q] = fmaf(wj, a0, o0[q]);
            o1[q] = fmaf(wj, a1, o1[q]);
            o2[q] = fmaf(wj, a2, o2[q]);
            o3[q] = fmaf(wj, a3, o3[q]);
        }
    }

    size_t base = (size_t)(2 * i) * W1_ + 2 * j;
#pragma unroll
    for (int c = 0; c < 3; c++) {
        *(float2*)(out + (size_t)c * HWF + base)       = make_float2(o0[c], o1[c]);
        *(float2*)(out + (size_t)c * HWF + base + W1_) = make_float2(o2[c], o3[c]);
        *(float2*)(out + OUT_LS + (size_t)c * HWF + base)       = make_float2(o0[c + 3], o1[c + 3]);
        *(float2*)(out + OUT_LS + (size_t)c * HWF + base + W1_) = make_float2(o2[c + 3], o3[c + 3]);
        *(float2*)(out + OUT_DEC + (size_t)c * HWF + base) =
            make_float2(fminf(fmaxf(o0[c], 0.0f), 1.0f), fminf(fmaxf(o1[c], 0.0f), 1.0f));
        *(float2*)(out + OUT_DEC + (size_t)c * HWF + base + W1_) =
            make_float2(fminf(fmaxf(o2[c], 0.0f), 1.0f), fminf(fmaxf(o3[c], 0.0f), 1.0f));
    }
}

// ---------------- launch ----------------
extern "C" void kernel_launch(void* const* d_in, const int* in_sizes, int n_in,
                              void* d_out, int out_size, void* d_ws, size_t ws_size,
                              hipStream_t stream) {
    const float* lat[7];
    for (int i = 0; i < 7; i++) lat[i] = (const float*)d_in[i];
    const float* noise  = (const float*)d_in[7];
    const float* arm_w1 = (const float*)d_in[8];
    const float* arm_b1 = (const float*)d_in[9];
    const float* arm_w2 = (const float*)d_in[10];
    const float* arm_b2 = (const float*)d_in[11];
    const float* arm_wo = (const float*)d_in[12];
    const float* arm_bo = (const float*)d_in[13];
    const float* ups_k  = (const float*)d_in[14]; // (6,8)
    const float* pre_k  = (const float*)d_in[15]; // (6,7)
    const float* syn_w1 = (const float*)d_in[16]; // (48,7)
    const float* syn_b1 = (const float*)d_in[17];
    const float* syn_w2 = (const float*)d_in[18]; // (6,48)
    const float* syn_b2 = (const float*)d_in[19];
    float* out = (float*)d_out;

    float* flat_q = (float*)d_ws;                 // N_TOTAL
    float* bufA   = flat_q + N_TOTAL;             // up to 6*512*768
    float* bufB   = bufA + 6 * 512 * 768;         // up to 5*256*384

    static const int SH[7]  = {1024, 512, 256, 128, 64, 32, 16};
    static const int SW[7]  = {1536, 768, 384, 192, 96, 48, 24};
    static const int OFF[7] = {OFF0, OFF1, OFF2, OFF3, OFF4, OFF5, OFF6};

    // 1. quantization
    quant_kernel<<<(N_TOTAL + 255) / 256, 256, 0, stream>>>(
        lat[0], lat[1], lat[2], lat[3], lat[4], lat[5], lat[6], noise, flat_q);

    // 2. fused ARM + rate (all 7 grids, one launch)
    arm_all_kernel<<<8192, 256, 0, stream>>>(flat_q, arm_w1, arm_b1, arm_w2, arm_b2,
                                             arm_wo, arm_bo, out + OUT_RATE);

    // 3. intermediate pyramid steps s=0..4 (quad kernels), ping-pong bufA/bufB
    const float* xin = flat_q + OFF6; // dec[6], 1ch 16x24
    float* bufs[2] = {bufA, bufB};
    for (int s = 0; s < 5; s++) {
        int i    = 6 - s;
        int hin  = SH[i], win_ = SW[i];
        int hout = SH[i - 1], wout = SW[i - 1];
        int cin  = s + 1;
        float* xout = bufs[s & 1];
        dim3 blk(16, 16);
        dim3 grd((wout / 2 + 15) / 16, (hout / 2 + 15) / 16, cin + 1);
        pyramid_quad_kernel<<<grd, blk, 0, stream>>>(xin, hin, win_,
                                                     flat_q + OFF[i - 1],
                                                     ups_k + s * 8, pre_k + s * 7,
                                                     xout, hout, wout);
        xin = xout;
    }

    // 4. fused final step + synthesis
    dim3 fgrd(768 / 16, 512 / 16);
    final_kernel<<<fgrd, 256, 0, stream>>>(bufA, flat_q,
                                           ups_k + 5 * 8, pre_k + 5 * 7,
                                           syn_w1, syn_b1, syn_w2, syn_b2, out);
}